// Round 4
// baseline (9352.076 us; speedup 1.0000x reference)
//
#include <hip/hip_runtime.h>

// Problem constants
#define NROWS 16384      // 8 * (8*16*16)
#define NE 8192
#define KSPL 8
#define KPER (NE / KSPL) // 1024
#define OUT_LOSS 4194304
#define OUT_IDX  4194305

// ---------------- S1[n] = np.sum(zf*zf, axis=1) bit-exact emulation ----------------
// numpy pairwise_sum over 256 contiguous fp32: split 128+128; each 128-block:
// 8 accumulators r[j] += w[8t+j] (t ascending), tree ((r0+r1)+(r2+r3))+((r4+r5)+(r6+r7));
// final S1 = blk0 + blk1. All fp32, no fma, no reassociation.
__global__ void k_s1(const float* __restrict__ Z, float* __restrict__ S1) {
#pragma clang fp contract(off)
    const int n = blockIdx.x * 256 + threadIdx.x;
    const int b = n >> 11, m = n & 2047;
    const float* zp = Z + b * 524288 + m;   // element c at zp[c*2048]
    float blk[2];
#pragma unroll
    for (int h = 0; h < 2; ++h) {
        float r[8];
#pragma unroll
        for (int j = 0; j < 8; ++j) {
            float z = zp[(h * 128 + j) * 2048];
            float w = z * z;
            asm("" : "+v"(w));
            r[j] = w;
        }
        for (int t2 = 1; t2 < 16; ++t2) {
#pragma unroll
            for (int j = 0; j < 8; ++j) {
                float z = zp[(h * 128 + t2 * 8 + j) * 2048];
                float w = z * z;
                asm("" : "+v"(w));
                r[j] += w;
            }
        }
        float s01 = r[0] + r[1], s23 = r[2] + r[3];
        float s45 = r[4] + r[5], s67 = r[6] + r[7];
        blk[h] = (s01 + s23) + (s45 + s67);
    }
    S1[n] = blk[0] + blk[1];
}

// ---------------- np-fp32-emulated argmin over k ----------------
// SSE einsum emulation: 4 sequential chains A_j (c == j mod 4), combined as
// fl(fl(A0+A1)+fl(A2+A3)). Here lane h (= t&1) owns chains {2h, 2h+1} whose
// elements (c = 4u+2h, 4u+2h+1) are CONTIGUOUS -> float2 e-loads, ILP-2.
// s_h = A_2h + A_{2h+1} is a tree node; P = s_h + shfl_xor(s_h,1) completes the
// tree (lane1 computes the commuted-but-bit-identical sum). dist = fl(S1 - 2P)
// (S2 < 0.5 ulp(S1), absorbed). k-unroll x2 = 4 independent chains in flight.
// Strict < scan, k ascending -> first-occurrence argmin per k-split.
__launch_bounds__(256, 3)
__global__ void k_np(const float* __restrict__ Z, const float* __restrict__ E,
                     const float* __restrict__ S1, float2* __restrict__ part) {
#pragma clang fp contract(off)
    const int t = threadIdx.x;
    const int h = t & 1;                 // chain-pair owner
    const int rb = blockIdx.x >> 3;      // row-block (128 rows)
    const int ks = blockIdx.x & 7;       // k-split
    const int n = rb * 128 + (t >> 1);
    const int b = n >> 11, m = n & 2047;

    // z slice: zx[u] = z[4u+2h], zy[u] = z[4u+2h+1]; pinned in VGPRs.
    const float* zp = Z + b * 524288 + m;
    float zx[64], zy[64];
#pragma unroll
    for (int u = 0; u < 64; ++u) {
        zx[u] = zp[(4 * u + 2 * h) * 2048];
        zy[u] = zp[(4 * u + 2 * h + 1) * 2048];
    }
#pragma unroll
    for (int u = 0; u < 64; ++u) { asm("" : "+v"(zx[u]), "+v"(zy[u])); }

    const float s1 = S1[n];
    float best = INFINITY;
    int bi = 0;

    const int k0 = ks * KPER;
    for (int k = k0; k < k0 + KPER; k += 2) {
        const float2* ep0 = reinterpret_cast<const float2*>(E + k * 256) + h;
        const float2* ep1 = reinterpret_cast<const float2*>(E + (k + 1) * 256) + h;
        float a0 = 0.f, a1 = 0.f, c0 = 0.f, c1 = 0.f;
#pragma unroll
        for (int u = 0; u < 64; ++u) {
            float2 e0 = ep0[2 * u];
            float2 e1 = ep1[2 * u];
            float p0 = zx[u] * e0.x; asm("" : "+v"(p0)); a0 += p0;
            float p1 = zy[u] * e0.y; asm("" : "+v"(p1)); a1 += p1;
            float q0 = zx[u] * e1.x; asm("" : "+v"(q0)); c0 += q0;
            float q1 = zy[u] * e1.y; asm("" : "+v"(q1)); c1 += q1;
        }
        float sa = a0 + a1;                   // h=0: fl(A0+A1); h=1: fl(A2+A3)
        float Pa = sa + __shfl_xor(sa, 1);    // fl((A0+A1)+(A2+A3))
        float da = s1 - 2.0f * Pa;
        if (da < best) { best = da; bi = k; }
        float sb = c0 + c1;
        float Pb = sb + __shfl_xor(sb, 1);
        float db = s1 - 2.0f * Pb;
        if (db < best) { best = db; bi = k + 1; }
    }
    if (h == 0) part[n * KSPL + ks] = make_float2(best, __int_as_float(bi));
}

// ---------------- merge k-splits (strict <, ks ascending) ----------------
__global__ void k_merge(const float2* __restrict__ part, int* __restrict__ idxv,
                        float* __restrict__ out) {
    const int n = blockIdx.x * 256 + threadIdx.x;
    float best = INFINITY;
    int bi = 0;
#pragma unroll
    for (int ks = 0; ks < KSPL; ++ks) {
        float2 pr = part[n * KSPL + ks];
        if (pr.x < best) { best = pr.x; bi = __float_as_int(pr.y); }
    }
    idxv[n] = bi;
    out[OUT_IDX + n] = (float)bi;
}

// ---------------- fp64 ||z - e_idx||^2 per row (for the loss) ----------------
__global__ void k_dmin(const float* __restrict__ Z, const float* __restrict__ E,
                       const int* __restrict__ idxv, double* __restrict__ dmin) {
    const int n = blockIdx.x * 4 + (threadIdx.x >> 6);
    const int lane = threadIdx.x & 63;
    const int b = n >> 11, m = n & 2047;
    const int kk = idxv[n];
    const float4 e4 = reinterpret_cast<const float4*>(E + kk * 256)[lane];
    const float* zp = Z + b * 524288 + m;
    double d0 = (double)zp[(4 * lane + 0) * 2048] - (double)e4.x;
    double d1 = (double)zp[(4 * lane + 1) * 2048] - (double)e4.y;
    double d2 = (double)zp[(4 * lane + 2) * 2048] - (double)e4.z;
    double d3 = (double)zp[(4 * lane + 3) * 2048] - (double)e4.w;
    double d = d0 * d0 + d1 * d1 + d2 * d2 + d3 * d3;
    for (int o = 32; o; o >>= 1) d += __shfl_xor(d, o);
    if (lane == 0) dmin[n] = d;
}

// ---------------- gather z_q with LDS transpose ----------------
__global__ void k_gather(const float* __restrict__ emb, const int* __restrict__ idxv,
                         float* __restrict__ out) {
    __shared__ float tile[32][33];
    __shared__ int kidx[32];
    const int blk = blockIdx.x;
    const int ct = blk & 7;
    const int mt = (blk >> 3) & 63;
    const int b = blk >> 9;
    const int t = threadIdx.x, tr = t >> 5, tc = t & 31;

    if (t < 32) kidx[t] = idxv[b * 2048 + mt * 32 + t];
    __syncthreads();
#pragma unroll
    for (int rr = 0; rr < 4; ++rr) {
        int row = tr + rr * 8;                                // m_local
        tile[row][tc] = emb[kidx[row] * 256 + ct * 32 + tc];  // coalesced along c
    }
    __syncthreads();
#pragma unroll
    for (int rr = 0; rr < 4; ++rr) {
        int cl = tr + rr * 8;                                 // c_local
        out[b * 524288 + (ct * 32 + cl) * 2048 + mt * 32 + tc] = tile[tc][cl];
    }
}

// ---------------- final loss reduce ----------------
__global__ void k_loss(const double* __restrict__ dmin, float* __restrict__ out) {
    __shared__ double sm[256];
    double s = 0.0;
    for (int i = threadIdx.x; i < NROWS; i += 256) s += dmin[i];
    sm[threadIdx.x] = s;
    __syncthreads();
    for (int o = 128; o; o >>= 1) {
        if (threadIdx.x < o) sm[threadIdx.x] += sm[threadIdx.x + o];
        __syncthreads();
    }
    if (threadIdx.x == 0)
        out[OUT_LOSS] = (float)(1.25 * sm[0] / 4194304.0);
}

// ---------------- launch ----------------
extern "C" void kernel_launch(void* const* d_in, const int* in_sizes, int n_in,
                              void* d_out, int out_size, void* d_ws, size_t ws_size,
                              hipStream_t stream) {
    const float* Z = (const float*)d_in[0];   // [8,256,8,16,16] fp32
    const float* E = (const float*)d_in[1];   // [8192,256] fp32
    float* out = (float*)d_out;
    char* ws = (char*)d_ws;

    float*  S1   = (float*)ws;                                    // 64 KB
    float2* part = (float2*)(ws + (64 << 10));                    // 1 MB
    double* dmin = (double*)(ws + (64 << 10) + (1 << 20));        // 128 KB
    int*    idxv = (int*)(ws + (64 << 10) + (1 << 20) + (128 << 10)); // 64 KB

    hipLaunchKernelGGL(k_s1,     dim3(64),   dim3(256), 0, stream, Z, S1);
    hipLaunchKernelGGL(k_np,     dim3(1024), dim3(256), 0, stream, Z, E, S1, part);
    hipLaunchKernelGGL(k_merge,  dim3(64),   dim3(256), 0, stream, part, idxv, out);
    hipLaunchKernelGGL(k_dmin,   dim3(4096), dim3(256), 0, stream, Z, E, idxv, dmin);
    hipLaunchKernelGGL(k_gather, dim3(4096), dim3(256), 0, stream, E, idxv, out);
    hipLaunchKernelGGL(k_loss,   dim3(1),    dim3(256), 0, stream, dmin, out);
}